// Round 5
// baseline (211.921 us; speedup 1.0000x reference)
//
#include <hip/hip_runtime.h>
#include <stdint.h>

#define NT 2048
#define DT 128

typedef __bf16 bf16x8 __attribute__((ext_vector_type(8)));
typedef __bf16 bf16x2 __attribute__((ext_vector_type(2)));
typedef float  f32x16 __attribute__((ext_vector_type(16)));

__device__ __forceinline__ float sigm(float x) {
    // sigmoid(x/sqrt(128)) = 1 / (1 + exp2(x * -log2(e)/sqrt(128)))
    return __builtin_amdgcn_rcpf(1.0f + __builtin_amdgcn_exp2f(x * -0.12753139620763842f));
}
__device__ __forceinline__ int pk2(float a, float b) {
    bf16x2 p; p[0] = (__bf16)a; p[1] = (__bf16)b;
    return __builtin_bit_cast(int, p);
}

// mfma_f32_32x32x16_bf16:
//  A: lane holds A[row=lane&31][k=(lane>>5)*8+j]
//  B: lane holds B[k=(lane>>5)*8+j][col=lane&31]
//  C/D: col=lane&31, row=(reg&3)+8*(reg>>2)+4*(lane>>5)
//
// Ping-pong pipeline: region between barriers holds GEMM2(i) AND
// GEMM1+sigmoid(i+1) — independent streams (separate accumulators, separate
// LDS buffers) so MFMA, trans, and LDS issue interleave instead of the R4
// serial phase chain. S fragments cross the barrier in registers (bfr[16]).
__global__ __launch_bounds__(512, 4)
void sig_attn(const float* __restrict__ Q, const float* __restrict__ K,
              const float* __restrict__ V, float* __restrict__ out)
{
    __shared__ __align__(16) __bf16 Qs[2][64 * 128];   // [n][d], granules xor'd by n&15
    __shared__ __align__(16) __bf16 Vs[2][128 * 64];   // [v][n], granules xor'd by v&7

    const int t   = threadIdx.x;
    const int w   = t >> 6;
    const int l   = t & 63;
    const int lq  = l >> 5;
    const int l31 = l & 31;
    const int lx  = l ^ 32;
    const int wm  = w & 3;       // 32-wide m-column
    const int wv  = w >> 2;      // 64-wide v-half

    const int bid    = blockIdx.x;
    const int b      = bid & 7;
    const int mt     = (bid >> 3) & 15;
    const int ns     = bid >> 7;
    const int m_blk  = mt * 128;
    const int n_base = ns * 512;

    const float* Qb = Q + (size_t)b * DT * NT;
    const float* Kb = K + (size_t)b * DT * NT;
    const float* Vb = V + (size_t)b * DT * NT;
    float*       Ob = out + (size_t)b * DT * NT;

    const int mrow = 32 * wm + l31;

    int pf_q[8], pf_v[8];   // bf16-packed prefetch (halved sustained regs)

    auto PREFETCH = [&](int n0) {
        #pragma unroll
        for (int r = 0; r < 2; ++r) {
            float f[8];
            #pragma unroll
            for (int j = 0; j < 8; ++j)
                f[j] = Qb[(size_t)(64 * r + 8 * w + j) * NT + n0 + l];
            #pragma unroll
            for (int u = 0; u < 4; ++u) pf_q[4 * r + u] = pk2(f[2 * u], f[2 * u + 1]);
        }
        const float* vb = Vb + (size_t)(t >> 2) * NT + n0 + 8 * (t & 3);
        const float4 a = *(const float4*)(vb);
        const float4 bb = *(const float4*)(vb + 4);
        const float4 c = *(const float4*)(vb + 32);
        const float4 d = *(const float4*)(vb + 36);
        pf_v[0] = pk2(a.x, a.y);  pf_v[1] = pk2(a.z, a.w);
        pf_v[2] = pk2(bb.x, bb.y); pf_v[3] = pk2(bb.z, bb.w);
        pf_v[4] = pk2(c.x, c.y);  pf_v[5] = pk2(c.z, c.w);
        pf_v[6] = pk2(d.x, d.y);  pf_v[7] = pk2(d.z, d.w);
    };

    auto STORE = [&](int buf) {
        __bf16* Qd = Qs[buf];
        __bf16* Vd = Vs[buf];
        #pragma unroll
        for (int r = 0; r < 2; ++r) {
            union { int i[4]; bf16x8 v; } u;
            #pragma unroll
            for (int k = 0; k < 4; ++k) u.i[k] = pf_q[4 * r + k];
            *(bf16x8*)&Qd[l * 128 + (((8 * r + w) ^ (l & 15)) * 8)] = u.v;
        }
        const int v = t >> 2;
        #pragma unroll
        for (int uu = 0; uu < 2; ++uu) {
            const int g = (t & 3) + 4 * uu;
            union { int i[4]; bf16x8 vv; } u2;
            #pragma unroll
            for (int k = 0; k < 4; ++k) u2.i[k] = pf_v[4 * uu + k];
            *(bf16x8*)&Vd[v * 64 + ((g ^ (v & 7)) * 8)] = u2.vv;
        }
    };

    // ---- K -> register B-frags: kf[k][j] = K[d=16k+8lq+j][m_blk+mrow]
    bf16x8 kf[8];

    auto GEMM1SIG = [&](int buf, int* bfr) {
        const __bf16* Qd = Qs[buf];
        #pragma unroll
        for (int h = 0; h < 2; ++h) {
            f32x16 sacc;
            #pragma unroll
            for (int r = 0; r < 16; ++r) sacc[r] = 0.0f;
            const int nrow = 32 * h + l31;
            #pragma unroll
            for (int k = 0; k < 8; ++k) {
                const bf16x8 af =
                    *(const bf16x8*)&Qd[nrow * 128 + (((2 * k + lq) ^ (nrow & 15)) * 8)];
                sacc = __builtin_amdgcn_mfma_f32_32x32x16_bf16(af, kf[k], sacc, 0, 0, 0);
            }
            int Pi[8];
            #pragma unroll
            for (int i = 0; i < 8; ++i)
                Pi[i] = pk2(sigm(sacc[2 * i]), sigm(sacc[2 * i + 1]));
            #pragma unroll
            for (int s = 0; s < 2; ++s) {
                const int x  = lq ? Pi[4 * s + 0] : Pi[4 * s + 2];
                const int y  = lq ? Pi[4 * s + 1] : Pi[4 * s + 3];
                const int xs = __shfl(x, lx, 64);
                const int ys = __shfl(y, lx, 64);
                int* o = &bfr[(2 * h + s) * 4];
                o[0] = lq ? xs : Pi[4 * s + 0];
                o[1] = lq ? ys : Pi[4 * s + 1];
                o[2] = lq ? Pi[4 * s + 2] : xs;
                o[3] = lq ? Pi[4 * s + 3] : ys;
            }
        }
    };

    f32x16 oacc[2];
    #pragma unroll
    for (int tv = 0; tv < 2; ++tv)
        #pragma unroll
        for (int r = 0; r < 16; ++r) oacc[tv][r] = 0.0f;

    auto GEMM2 = [&](int buf, const int* bfr) {
        const __bf16* Vd = Vs[buf];
        #pragma unroll
        for (int h = 0; h < 2; ++h) {
            #pragma unroll
            for (int s = 0; s < 2; ++s) {
                union { int i[4]; bf16x8 v; } u;
                #pragma unroll
                for (int k = 0; k < 4; ++k) u.i[k] = bfr[(2 * h + s) * 4 + k];
                const int sl = ((4 * h + 2 * s + lq) ^ (l31 & 7)) * 8;
                const bf16x8 av0 = *(const bf16x8*)&Vd[(64 * wv + l31) * 64 + sl];
                const bf16x8 av1 = *(const bf16x8*)&Vd[(64 * wv + 32 + l31) * 64 + sl];
                oacc[0] = __builtin_amdgcn_mfma_f32_32x32x16_bf16(av0, u.v, oacc[0], 0, 0, 0);
                oacc[1] = __builtin_amdgcn_mfma_f32_32x32x16_bf16(av1, u.v, oacc[1], 0, 0, 0);
            }
        }
    };

    // ================= prologue =================
    PREFETCH(n_base);                 // chunk 0
    {   // K preload (overlaps prefetch latency)
        #pragma unroll
        for (int half = 0; half < 2; ++half) {
            float tmp[4][8];
            #pragma unroll
            for (int k2 = 0; k2 < 4; ++k2)
                #pragma unroll
                for (int j = 0; j < 8; ++j)
                    tmp[k2][j] = Kb[(size_t)((half * 4 + k2) * 16 + lq * 8 + j) * NT
                                    + m_blk + mrow];
            #pragma unroll
            for (int k2 = 0; k2 < 4; ++k2) {
                bf16x8 f;
                #pragma unroll
                for (int j = 0; j < 8; ++j) f[j] = (__bf16)tmp[k2][j];
                kf[half * 4 + k2] = f;
            }
        }
    }
    STORE(0);
    PREFETCH(n_base + 64);            // chunk 1
    __syncthreads();                  // B: chunk 0 ready
    int bfr[16];
    GEMM1SIG(0, bfr);

    // ================= main loop =================
    // region after beta_it holds GEMM2(it) + GEMM1SIG(it+1): independent streams.
    #pragma unroll
    for (int it = 0; it < 7; ++it) {
        if (it) __syncthreads();      // barrier2: GEMM2(it-1)/GEMM1SIG(it) reads done
        STORE((it + 1) & 1);          // consumes prefetch of chunk it+1
        if (it < 6) PREFETCH(n_base + (it + 2) * 64);
        __syncthreads();              // beta_it: chunk it+1 staged
        GEMM2(it & 1, bfr);
        GEMM1SIG((it + 1) & 1, bfr);  // register-renamed; independent of GEMM2(it)
    }
    GEMM2(1, bfr);                    // chunk 7 (staged before beta_6)

    // ================= epilogue: merge 4 n-split partials =================
    #pragma unroll
    for (int tv = 0; tv < 2; ++tv) {
        #pragma unroll
        for (int r = 0; r < 16; ++r) {
            const int v = 64 * wv + 32 * tv + (r & 3) + 8 * (r >> 2) + 4 * lq;
            atomicAdd(&Ob[(size_t)v * NT + m_blk + mrow], oacc[tv][r]);
        }
    }
}

extern "C" void kernel_launch(void* const* d_in, const int* in_sizes, int n_in,
                              void* d_out, int out_size, void* d_ws, size_t ws_size,
                              hipStream_t stream) {
    (void)in_sizes; (void)n_in; (void)d_ws; (void)ws_size;
    const float* Q = (const float*)d_in[0];
    const float* K = (const float*)d_in[1];
    const float* V = (const float*)d_in[2];
    float* O = (float*)d_out;
    // harness re-poisons d_out with 0xAA before every launch; atomics need zeros
    hipMemsetAsync(d_out, 0, (size_t)out_size * sizeof(float), stream);
    sig_attn<<<dim3(512), dim3(512), 0, stream>>>(Q, K, V, O);
}

// Round 6
// 134.783 us; speedup vs baseline: 1.5723x; 1.5723x over previous
//
#include <hip/hip_runtime.h>
#include <stdint.h>

#define NT 2048
#define DT 128

typedef __bf16 bf16x8 __attribute__((ext_vector_type(8)));
typedef __bf16 bf16x4 __attribute__((ext_vector_type(4)));
typedef __bf16 bf16x2 __attribute__((ext_vector_type(2)));
typedef float  f32x16 __attribute__((ext_vector_type(16)));

__device__ __forceinline__ float sigm(float x) {
    // sigmoid(x/sqrt(128)) = 1/(1 + exp2(x * -log2(e)/sqrt(128)))
    return __builtin_amdgcn_rcpf(1.0f + __builtin_amdgcn_exp2f(x * -0.12753139620763842f));
}
__device__ __forceinline__ int pk2f(float a, float b) {
    bf16x2 p; p[0] = (__bf16)a; p[1] = (__bf16)b;
    return __builtin_bit_cast(int, p);
}

// mfma_f32_32x32x16_bf16:
//  A: lane holds A[row=lane&31][k=(lane>>5)*8+j]
//  B: lane holds B[k=(lane>>5)*8+j][col=lane&31]
//  C/D: col=lane&31, row=(reg&3)+8*(reg>>2)+4*(lane>>5)

// ============================ Kernel 1 ============================
// ST[b'][m][n] = sigmoid(sum_d Q[d][n]K[d][m]/sqrt(128)), bf16, n contiguous.
// grid 512 = bpp x 16 mt x ns ; 512 thr = 8 waves (wm 0..3, nh 0..1)
__global__ __launch_bounds__(512, 4)
void k1_sig(const float* __restrict__ Q, const float* __restrict__ Kg,
            __bf16* __restrict__ ST, int b_off, int bpp_log, int nchunks)
{
    __shared__ __align__(16) __bf16 Qs[64 * 128];   // [n][d], granule (d>>3)^(n&15)
    __shared__ __align__(16) __bf16 Ss[128 * 64];   // [m][n], granule (n>>3)^(m&7)

    const int t = threadIdx.x;
    const int w = t >> 6, l = t & 63, lq = l >> 5, l31 = l & 31;
    const int wm = w & 3, nh = w >> 2;

    const int bid = blockIdx.x;
    const int b   = (bid & ((1 << bpp_log) - 1)) + b_off;
    const int mt  = (bid >> bpp_log) & 15;
    const int ns  = bid >> (bpp_log + 4);
    const int m_blk  = mt * 128;
    const int n_base = ns * (nchunks * 64);

    const float* Qb = Q  + (size_t)b * DT * NT;
    const float* Kb = Kg + (size_t)b * DT * NT;
    __bf16* STb = ST + ((size_t)(b - b_off) * 2048 + m_blk) * 2048;  // pass-local

    const int mrow = 32 * wm + l31;

    // K -> register B-frags: kf[k][j] = K[d=16k+8lq+j][m_blk+mrow]
    bf16x8 kf[8];
    #pragma unroll
    for (int half = 0; half < 2; ++half) {
        float tmp[4][8];
        #pragma unroll
        for (int k2 = 0; k2 < 4; ++k2)
            #pragma unroll
            for (int j = 0; j < 8; ++j)
                tmp[k2][j] = Kb[(size_t)((half * 4 + k2) * 16 + lq * 8 + j) * NT + m_blk + mrow];
        #pragma unroll
        for (int k2 = 0; k2 < 4; ++k2) {
            bf16x8 f;
            #pragma unroll
            for (int j = 0; j < 8; ++j) f[j] = (__bf16)tmp[k2][j];
            kf[half * 4 + k2] = f;
        }
    }

    int qp[8];   // bf16-packed Q prefetch: thread covers n=l, d = 64r+8w .. +7
    auto PREF = [&](int n0) {
        #pragma unroll
        for (int r = 0; r < 2; ++r) {
            float f[8];
            #pragma unroll
            for (int j = 0; j < 8; ++j)
                f[j] = Qb[(size_t)(64 * r + 8 * w + j) * NT + n0 + l];
            #pragma unroll
            for (int u = 0; u < 4; ++u) qp[4 * r + u] = pk2f(f[2 * u], f[2 * u + 1]);
        }
    };
    auto STQ = [&]() {
        #pragma unroll
        for (int r = 0; r < 2; ++r) {
            union { int i[4]; bf16x8 v; } u;
            #pragma unroll
            for (int k = 0; k < 4; ++k) u.i[k] = qp[4 * r + k];
            *(bf16x8*)&Qs[l * 128 + (((8 * r + w) ^ (l & 15)) * 8)] = u.v;
        }
    };

    PREF(n_base);
    STQ();
    if (nchunks > 1) PREF(n_base + 64);
    __syncthreads();

    for (int it = 0; it < nchunks; ++it) {
        // GEMM1, two independent accumulator chains (halved dep latency)
        const int nrow = 32 * nh + l31;
        f32x16 sa, sb;
        #pragma unroll
        for (int r = 0; r < 16; ++r) { sa[r] = 0.0f; sb[r] = 0.0f; }
        #pragma unroll
        for (int k = 0; k < 4; ++k) {
            const bf16x8 a0 =
                *(const bf16x8*)&Qs[nrow * 128 + (((2 * k + lq) ^ (nrow & 15)) * 8)];
            const bf16x8 a1 =
                *(const bf16x8*)&Qs[nrow * 128 + (((2 * (k + 4) + lq) ^ (nrow & 15)) * 8)];
            sa = __builtin_amdgcn_mfma_f32_32x32x16_bf16(a0, kf[k], sa, 0, 0, 0);
            sb = __builtin_amdgcn_mfma_f32_32x32x16_bf16(a1, kf[k + 4], sb, 0, 0, 0);
        }
        #pragma unroll
        for (int r = 0; r < 16; ++r) sa[r] += sb[r];

        // sigmoid -> Ss[m][n] : 4 runs of 4 consecutive n (b64 writes)
        #pragma unroll
        for (int ii = 0; ii < 4; ++ii) {
            bf16x4 pk;
            #pragma unroll
            for (int rr = 0; rr < 4; ++rr) pk[rr] = (__bf16)sigm(sa[4 * ii + rr]);
            const int nl = 32 * nh + 8 * ii + 4 * lq;   // rows (r&3)+8*(r>>2)+4lq
            *(bf16x4*)&Ss[mrow * 64 + (((nl >> 3) ^ (mrow & 7)) * 8) + (nl & 7)] = pk;
        }
        __syncthreads();   // B: Ss ready; Qs A-frag reads done

        // Ss -> global ST (coalesced 16B stores)
        {
            const int m  = t >> 2;
            const int nb = t & 3;
            const size_t gb = (size_t)m * 2048 + n_base + it * 64 + 16 * nb;
            #pragma unroll
            for (int q = 0; q < 2; ++q) {
                const bf16x8 v =
                    *(const bf16x8*)&Ss[m * 64 + (((2 * nb + q) ^ (m & 7)) * 8)];
                *(bf16x8*)&STb[gb + 8 * q] = v;
            }
        }
        if (it + 1 < nchunks) {
            STQ();                                   // safe: GEMM1(it) reads pre-B
            if (it + 2 < nchunks) PREF(n_base + (it + 2) * 64);
        }
        __syncthreads();   // A: Qs(it+1) staged; Ss reads done
    }
}

// ============================ Kernel 2 ============================
// out[b][v][m] += sum_n V[v][n] * ST[m][n].  Transpose-free staging.
// grid 512 = bpp x 16 mt x ks ; 512 thr = 8 waves (wm 0..3, wv 0..1)
__global__ __launch_bounds__(512, 4)
void k2_vs(const float* __restrict__ V, const __bf16* __restrict__ ST,
           float* __restrict__ out, int b_off, int bpp_log, int nchunks)
{
    __shared__ __align__(16) __bf16 Vs[2][128 * 64];  // [v][n], granule (n>>3)^(v&7)
    __shared__ __align__(16) __bf16 Ts[2][128 * 64];  // [m][n], granule (n>>3)^(m&7)

    const int t = threadIdx.x;
    const int w = t >> 6, l = t & 63, lq = l >> 5, l31 = l & 31;
    const int wm = w & 3, wv = w >> 2;

    const int bid = blockIdx.x;
    const int b   = (bid & ((1 << bpp_log) - 1)) + b_off;
    const int mt  = (bid >> bpp_log) & 15;
    const int ks  = bid >> (bpp_log + 4);
    const int m_blk  = mt * 128;
    const int n_base = ks * (nchunks * 64);

    const float*  Vb  = V + (size_t)b * DT * NT;
    const __bf16* STb = ST + ((size_t)(b - b_off) * 2048 + m_blk) * 2048;
    float*        Ob  = out + (size_t)b * DT * NT;

    const int row = t >> 2;      // staging row (both v and m)
    const int nb  = t & 3;       // 16-elem n-block

    int pv[8], pt[8];            // packed prefetch
    auto PREF = [&](int n0) {
        const float* vs = Vb + (size_t)row * NT + n0 + 16 * nb;
        const float4 a = ((const float4*)vs)[0];
        const float4 c = ((const float4*)vs)[1];
        const float4 d = ((const float4*)vs)[2];
        const float4 e = ((const float4*)vs)[3];
        pv[0] = pk2f(a.x, a.y); pv[1] = pk2f(a.z, a.w);
        pv[2] = pk2f(c.x, c.y); pv[3] = pk2f(c.z, c.w);
        pv[4] = pk2f(d.x, d.y); pv[5] = pk2f(d.z, d.w);
        pv[6] = pk2f(e.x, e.y); pv[7] = pk2f(e.z, e.w);
        const int4* ss = (const int4*)(STb + (size_t)row * 2048 + n0 + 16 * nb);
        const int4 s0 = ss[0], s1 = ss[1];
        pt[0] = s0.x; pt[1] = s0.y; pt[2] = s0.z; pt[3] = s0.w;
        pt[4] = s1.x; pt[5] = s1.y; pt[6] = s1.z; pt[7] = s1.w;
    };
    auto STG = [&](int buf) {
        #pragma unroll
        for (int q = 0; q < 2; ++q) {
            union { int i[4]; bf16x8 v; } u1, u2;
            #pragma unroll
            for (int k = 0; k < 4; ++k) { u1.i[k] = pv[4 * q + k]; u2.i[k] = pt[4 * q + k]; }
            const int g = ((2 * nb + q) ^ (row & 7)) * 8;
            *(bf16x8*)&Vs[buf][row * 64 + g] = u1.v;
            *(bf16x8*)&Ts[buf][row * 64 + g] = u2.v;
        }
    };

    f32x16 oacc[2];
    #pragma unroll
    for (int tv = 0; tv < 2; ++tv)
        #pragma unroll
        for (int r = 0; r < 16; ++r) oacc[tv][r] = 0.0f;

    PREF(n_base);
    STG(0);
    if (nchunks > 1) PREF(n_base + 64);
    __syncthreads();

    for (int it = 0; it < nchunks; ++it) {
        if (it + 1 < nchunks) {
            STG((it + 1) & 1);                       // other buffer: no conflict
            if (it + 2 < nchunks) PREF(n_base + (it + 2) * 64);
        }
        const __bf16* Vd = Vs[it & 1];
        const __bf16* Td = Ts[it & 1];
        #pragma unroll
        for (int k = 0; k < 4; ++k) {
            const int g = ((2 * k + lq) ^ (l31 & 7)) * 8;   // row&7 == l31&7 for all rows used
            const bf16x8 bs = *(const bf16x8*)&Td[(32 * wm + l31) * 64 + g];
            const bf16x8 a0 = *(const bf16x8*)&Vd[(64 * wv + l31) * 64 + g];
            const bf16x8 a1 = *(const bf16x8*)&Vd[(64 * wv + 32 + l31) * 64 + g];
            oacc[0] = __builtin_amdgcn_mfma_f32_32x32x16_bf16(a0, bs, oacc[0], 0, 0, 0);
            oacc[1] = __builtin_amdgcn_mfma_f32_32x32x16_bf16(a1, bs, oacc[1], 0, 0, 0);
        }
        __syncthreads();
    }

    // merge k-splits via atomics (measured cheap: ~2.5 us for 8.4M lane-atomics)
    #pragma unroll
    for (int tv = 0; tv < 2; ++tv) {
        #pragma unroll
        for (int r = 0; r < 16; ++r) {
            const int v = 64 * wv + 32 * tv + (r & 3) + 8 * (r >> 2) + 4 * lq;
            atomicAdd(&Ob[(size_t)v * NT + m_blk + 32 * wm + l31], oacc[tv][r]);
        }
    }
}

// ==================== Fallback: R4 fused kernel (proven 63 us) ====================
__global__ __launch_bounds__(512, 4)
void sig_attn_fused(const float* __restrict__ Q, const float* __restrict__ K,
                    const float* __restrict__ V, float* __restrict__ out)
{
    __shared__ __align__(16) __bf16 Qs[2][64 * 128];
    __shared__ __align__(16) __bf16 Vs[2][128 * 64];

    const int t = threadIdx.x;
    const int w = t >> 6, l = t & 63, lq = l >> 5, l31 = l & 31, lx = l ^ 32;
    const int wm = w & 3, wv = w >> 2;

    const int bid = blockIdx.x;
    const int b = bid & 7, mt = (bid >> 3) & 15, ns = bid >> 7;
    const int m_blk = mt * 128, n_base = ns * 512;

    const float* Qb = Q + (size_t)b * DT * NT;
    const float* Kb = K + (size_t)b * DT * NT;
    const float* Vb = V + (size_t)b * DT * NT;
    float*       Ob = out + (size_t)b * DT * NT;

    const int mrow = 32 * wm + l31;

    float  qp[16];
    float4 vp[4];
    {
        #pragma unroll
        for (int r = 0; r < 2; ++r)
            #pragma unroll
            for (int j = 0; j < 8; ++j)
                qp[r * 8 + j] = Qb[(size_t)(64 * r + 8 * w + j) * NT + n_base + l];
        const float* vb = Vb + (size_t)(t >> 2) * NT + n_base + 8 * (t & 3);
        vp[0] = *(const float4*)(vb);
        vp[1] = *(const float4*)(vb + 4);
        vp[2] = *(const float4*)(vb + 32);
        vp[3] = *(const float4*)(vb + 36);
    }

    bf16x8 kf[8];
    #pragma unroll
    for (int half = 0; half < 2; ++half) {
        float tmp[4][8];
        #pragma unroll
        for (int k2 = 0; k2 < 4; ++k2)
            #pragma unroll
            for (int j = 0; j < 8; ++j)
                tmp[k2][j] = Kb[(size_t)((half * 4 + k2) * 16 + lq * 8 + j) * NT + m_blk + mrow];
        #pragma unroll
        for (int k2 = 0; k2 < 4; ++k2) {
            bf16x8 f;
            #pragma unroll
            for (int j = 0; j < 8; ++j) f[j] = (__bf16)tmp[k2][j];
            kf[half * 4 + k2] = f;
        }
    }

    f32x16 oacc[2];
    #pragma unroll
    for (int tv = 0; tv < 2; ++tv)
        #pragma unroll
        for (int r = 0; r < 16; ++r) oacc[tv][r] = 0.0f;

    for (int it = 0; it < 8; ++it) {
        __bf16* Qbuf = Qs[it & 1];
        __bf16* Vbuf = Vs[it & 1];
        #pragma unroll
        for (int r = 0; r < 2; ++r) {
            bf16x8 pk;
            #pragma unroll
            for (int j = 0; j < 8; ++j) pk[j] = (__bf16)qp[r * 8 + j];
            *(bf16x8*)&Qbuf[l * 128 + (((8 * r + w) ^ (l & 15)) * 8)] = pk;
        }
        {
            const int v = t >> 2;
            #pragma unroll
            for (int u = 0; u < 2; ++u) {
                const int g = (t & 3) + 4 * u;
                const float* s = (const float*)&vp[2 * u];
                bf16x8 pk;
                #pragma unroll
                for (int j = 0; j < 8; ++j) pk[j] = (__bf16)s[j];
                *(bf16x8*)&Vbuf[v * 64 + ((g ^ (v & 7)) * 8)] = pk;
            }
        }
        __syncthreads();
        {
            const int n0 = n_base + ((it + 1) & 7) * 64;
            #pragma unroll
            for (int r = 0; r < 2; ++r)
                #pragma unroll
                for (int j = 0; j < 8; ++j)
                    qp[r * 8 + j] = Qb[(size_t)(64 * r + 8 * w + j) * NT + n0 + l];
            const float* vb = Vb + (size_t)(t >> 2) * NT + n0 + 8 * (t & 3);
            vp[0] = *(const float4*)(vb);
            vp[1] = *(const float4*)(vb + 4);
            vp[2] = *(const float4*)(vb + 32);
            vp[3] = *(const float4*)(vb + 36);
        }
        #pragma unroll
        for (int h = 0; h < 2; ++h) {
            f32x16 sacc;
            #pragma unroll
            for (int r = 0; r < 16; ++r) sacc[r] = 0.0f;
            const int nrow = 32 * h + l31;
            #pragma unroll
            for (int k = 0; k < 8; ++k) {
                const bf16x8 af =
                    *(const bf16x8*)&Qbuf[nrow * 128 + (((2 * k + lq) ^ (nrow & 15)) * 8)];
                sacc = __builtin_amdgcn_mfma_f32_32x32x16_bf16(af, kf[k], sacc, 0, 0, 0);
            }
            int Pi[8];
            #pragma unroll
            for (int i = 0; i < 8; ++i)
                Pi[i] = pk2f(sigm(sacc[2 * i]), sigm(sacc[2 * i + 1]));
            #pragma unroll
            for (int s = 0; s < 2; ++s) {
                const int x  = lq ? Pi[4 * s + 0] : Pi[4 * s + 2];
                const int y  = lq ? Pi[4 * s + 1] : Pi[4 * s + 3];
                const int xs = __shfl(x, lx, 64);
                const int ys = __shfl(y, lx, 64);
                union { int i[4]; bf16x8 v; } bf;
                bf.i[0] = lq ? xs : Pi[4 * s + 0];
                bf.i[1] = lq ? ys : Pi[4 * s + 1];
                bf.i[2] = lq ? Pi[4 * s + 2] : xs;
                bf.i[3] = lq ? Pi[4 * s + 3] : ys;
                const int sl  = ((4 * h + 2 * s + lq) ^ (l31 & 7)) * 8;
                const bf16x8 av0 = *(const bf16x8*)&Vbuf[(64 * wv + l31) * 64 + sl];
                const bf16x8 av1 = *(const bf16x8*)&Vbuf[(64 * wv + 32 + l31) * 64 + sl];
                oacc[0] = __builtin_amdgcn_mfma_f32_32x32x16_bf16(av0, bf.v, oacc[0], 0, 0, 0);
                oacc[1] = __builtin_amdgcn_mfma_f32_32x32x16_bf16(av1, bf.v, oacc[1], 0, 0, 0);
            }
        }
    }
    #pragma unroll
    for (int tv = 0; tv < 2; ++tv) {
        #pragma unroll
        for (int r = 0; r < 16; ++r) {
            const int v = 64 * wv + 32 * tv + (r & 3) + 8 * (r >> 2) + 4 * lq;
            atomicAdd(&Ob[(size_t)v * NT + m_blk + mrow], oacc[tv][r]);
        }
    }
}

extern "C" void kernel_launch(void* const* d_in, const int* in_sizes, int n_in,
                              void* d_out, int out_size, void* d_ws, size_t ws_size,
                              hipStream_t stream) {
    (void)in_sizes; (void)n_in;
    const float* Q = (const float*)d_in[0];
    const float* K = (const float*)d_in[1];
    const float* V = (const float*)d_in[2];
    float* O = (float*)d_out;

    const size_t per_batch = (size_t)2048 * 2048 * 2;   // 8.4 MB of bf16 S^T per batch
    int bpp = 0;                                        // batches per pass
    if      (ws_size >= 8 * per_batch) bpp = 8;
    else if (ws_size >= 4 * per_batch) bpp = 4;
    else if (ws_size >= 2 * per_batch) bpp = 2;

    hipMemsetAsync(d_out, 0, (size_t)out_size * sizeof(float), stream);
    if (bpp) {
        const int bpp_log = (bpp == 8) ? 3 : (bpp == 4) ? 2 : 1;
        const int nchunks = bpp;   // grid fixed at 512 => chunks/block == bpp
        for (int b_off = 0; b_off < 8; b_off += bpp) {
            k1_sig<<<dim3(512), dim3(512), 0, stream>>>(Q, K, (__bf16*)d_ws,
                                                        b_off, bpp_log, nchunks);
            k2_vs<<<dim3(512), dim3(512), 0, stream>>>(V, (const __bf16*)d_ws, O,
                                                       b_off, bpp_log, nchunks);
        }
    } else {
        sig_attn_fused<<<dim3(512), dim3(512), 0, stream>>>(Q, K, V, O);
    }
}